// Round 8
// baseline (192.956 us; speedup 1.0000x reference)
//
#include <hip/hip_runtime.h>
#include <hip/hip_bf16.h>

// Problem constants
#define DM   96
#define DI   192
#define BB   8
#define LL   4096
#define NCHUNK 128
#define CLEN   32
#define NSEG   8
#define SEGC   16
#define LOG2E  1.44269504f
#define LN2    0.69314718f

typedef __bf16 bf16_t;
typedef __attribute__((ext_vector_type(8))) __bf16 bf16x8;
typedef __attribute__((ext_vector_type(4))) __bf16 bf16x4;
typedef __attribute__((ext_vector_type(4))) float f32x4;

// Workspace layout (float offsets)
#define P_OFF    0u         // [B,128,192,8]
#define Q_OFF    786432u
#define KC_OFF   1572864u
#define PG_OFF   2359296u   // [B,8,192,8]
#define QG_OFF   2457600u
#define GG_OFF   2555904u
#define KG_OFF   2654208u
#define YP_OFF   2752512u   // [B,128,192]
#define UP_OFF   2949120u   // [B,128,96]
#define WBF_OFF  3047424u   // bf16 W_in [384][96]
#define WXB_OFF  3065856u   // bf16 W_x  [32pad][192]

// LDS layout (bytes). Aggressive overlay; lifetimes separated by barriers:
//   su  (fp32 34x100=13600) = EXACTLY sxh's region (su dead before epilogue)
//   sa  (bf16 48x104= 9984) inside szh's region  (sa dead after A-frag preload)
//   conv is done IN-PLACE in sxh (reads to regs, barrier, write-back).
#define L_SU   0u
#define L_SXH  0u        // bf16 34x200 = 13600
#define L_SA   13600u
#define L_SZH  13600u    // bf16 32x200 = 12800 -> ends 26400
#define L_SDT  26400u    // 32*8*4  = 1024
#define L_SBC  27424u    // 32*16*4 = 2048
#define L_SSC  29472u    // 34*4    = 136
#define L_TOT  29608u    // -> 5 blocks/CU (20 waves/CU), 1024 blocks resident

__device__ __forceinline__ float fast_silu(float v) {
  float ev = exp2f(-LOG2E * v);
  return __fdividef(v, 1.f + ev);
}

// ---------------------------------------------------------------------------
// K0: convert W_in -> bf16, W_x -> bf16 [32pad][192].
// ---------------------------------------------------------------------------
__global__ __launch_bounds__(256) void k_cvt(
    const float* __restrict__ W_in, const float* __restrict__ W_x,
    bf16_t* __restrict__ Wbf, bf16_t* __restrict__ Wxb)
{
  int i = blockIdx.x * 256 + threadIdx.x;
  if (i < 36864) Wbf[i] = (bf16_t)W_in[i];
  int j = i - 36864;
  if (j >= 0 && j < 6144) Wxb[j] = (j < 4224) ? (bf16_t)W_x[j] : (bf16_t)0.f;
}

// ---------------------------------------------------------------------------
// Fused: rmsnorm + in-proj MFMA + conv3/silu (in-place) + dbc MFMA + scan.
// Block = (b, chunk of 32 positions); 256 threads (4 waves); 5 blocks/CU.
// ---------------------------------------------------------------------------
__global__ __launch_bounds__(256, 5) void k_fused(
    const float* __restrict__ u, const float* __restrict__ norm_w,
    const bf16_t* __restrict__ Wbf, const bf16_t* __restrict__ Wxb,
    const float* __restrict__ conv_w, const float* __restrict__ conv_b,
    const float* __restrict__ W_dt, const float* __restrict__ b_dt,
    const float* __restrict__ A_log, const float* __restrict__ D_ssm,
    float* __restrict__ Pc, float* __restrict__ Qc, float* __restrict__ Kc,
    float* __restrict__ YP, float* __restrict__ UP)
{
  __shared__ __align__(16) char lds[L_TOT];
  float*  su  = (float*)(lds + L_SU);
  bf16_t* sxh = (bf16_t*)(lds + L_SXH);
  bf16_t* sa  = (bf16_t*)(lds + L_SA);
  bf16_t* szh = (bf16_t*)(lds + L_SZH);
  float*  sdt = (float*)(lds + L_SDT);
  float*  sbc = (float*)(lds + L_SBC);
  float*  ssc = (float*)(lds + L_SSC);

  const int tid = threadIdx.x;
  const int b   = blockIdx.x >> 7;
  const int c   = blockIdx.x & 127;
  const int wv  = tid >> 6, lane = tid & 63;
  const int q   = lane >> 4, nlo = lane & 15;
  const int l0  = c * CLEN - 2;

  // --- in-proj B fragments (bf16; L1-hot, compiler may re-load, no spill) ---
  bf16x8 Bf[6][3];
  #pragma unroll
  for (int nt = 0; nt < 6; ++nt)
    #pragma unroll
    for (int ks = 0; ks < 3; ++ks)
      Bf[nt][ks] = *(const bf16x8*)&Wbf[(wv * 96 + nt * 16 + nlo) * 96 + ks * 32 + q * 8];

  // --- stage u rows l0..l0+33 (fp32) ---
  for (int i = tid; i < 34 * 24; i += 256) {
    int p = i / 24, k4 = (i - p * 24) * 4;
    int l = l0 + p;
    float4 v = (l >= 0) ? *(const float4*)&u[(b * LL + l) * 96 + k4]
                        : make_float4(0.f, 0.f, 0.f, 0.f);
    *(float4*)&su[p * 100 + k4] = v;
  }
  __syncthreads();                                   // (1) su ready

  // --- rms scales + raw-u column partial sums ---
  if (tid < 34) {
    float s = 0.f;
    #pragma unroll
    for (int k4 = 0; k4 < 24; ++k4) {
      float4 v = *(const float4*)&su[tid * 100 + k4 * 4];
      s += v.x * v.x + v.y * v.y + v.z * v.z + v.w * v.w;
    }
    ssc[tid] = rsqrtf(s * (1.f / 96.f) + 1e-5f);
  } else if (tid >= 64 && tid < 160) {
    int k = tid - 64;
    float s = 0.f;
    #pragma unroll 8
    for (int p = 0; p < 32; ++p) s += su[(p + 2) * 100 + k];
    UP[(b * NCHUNK + c) * 96 + k] = s;
  }
  __syncthreads();                                   // (2) ssc ready

  // --- bf16 A tile (scale*norm_w folded); rows 34..47 garbage = discarded ---
  for (int i = tid; i < 34 * 24; i += 256) {
    int p = i / 24, k4 = (i - p * 24) * 4;
    float4 v = *(const float4*)&su[p * 100 + k4];
    float4 nw = *(const float4*)&norm_w[k4];
    float sc = ssc[p];
    bf16x4 o = {(bf16_t)(v.x * sc * nw.x), (bf16_t)(v.y * sc * nw.y),
                (bf16_t)(v.z * sc * nw.z), (bf16_t)(v.w * sc * nw.w)};
    *(bf16x4*)&sa[p * 104 + k4] = o;
  }
  __syncthreads();                                   // (3) sa ready

  // --- preload ALL A fragments to registers; sa/su dead afterwards ---
  bf16x8 Afr[3][3];
  #pragma unroll
  for (int mt = 0; mt < 3; ++mt) {
    const int arow = (mt * 16 + nlo) * 104 + q * 8;
    Afr[mt][0] = *(const bf16x8*)&sa[arow];
    Afr[mt][1] = *(const bf16x8*)&sa[arow + 32];
    Afr[mt][2] = *(const bf16x8*)&sa[arow + 64];
  }
  __syncthreads();                                   // (4) su/sa dead -> overlay OK

  // --- in-proj MFMA; epilogue: sxh = x half (overlays su), szh = silu(z) ---
  #pragma unroll
  for (int mt = 0; mt < 3; ++mt) {
    #pragma unroll
    for (int nt = 0; nt < 6; ++nt) {
      f32x4 acc = {0.f, 0.f, 0.f, 0.f};
      acc = __builtin_amdgcn_mfma_f32_16x16x32_bf16(Afr[mt][0], Bf[nt][0], acc, 0, 0, 0);
      acc = __builtin_amdgcn_mfma_f32_16x16x32_bf16(Afr[mt][1], Bf[nt][1], acc, 0, 0, 0);
      acc = __builtin_amdgcn_mfma_f32_16x16x32_bf16(Afr[mt][2], Bf[nt][2], acc, 0, 0, 0);
      int j = wv * 96 + nt * 16 + nlo;
      int row0 = mt * 16 + q * 4;
      if (j < 192) {
        #pragma unroll
        for (int r = 0; r < 4; ++r) {
          int row = row0 + r;
          if (row < 34) sxh[row * 200 + j] = (bf16_t)acc[r];
        }
      } else {
        int jj = j - 192;
        #pragma unroll
        for (int r = 0; r < 4; ++r) {
          int row = row0 + r;
          if (row >= 2 && row < 34) szh[(row - 2) * 200 + jj] = (bf16_t)fast_silu(acc[r]);
        }
      }
    }
  }
  __syncthreads();                                   // (5) sxh/szh ready

  // --- prefetch scan constants (latency hidden behind conv) ---
  float wdt[6], bdt = 0.f, Dd = 0.f, a2[8];
  if (tid < 192) {
    const int d = tid;
    float2 w01 = *(const float2*)&W_dt[d * 6];
    float2 w23 = *(const float2*)&W_dt[d * 6 + 2];
    float2 w45 = *(const float2*)&W_dt[d * 6 + 4];
    wdt[0] = w01.x; wdt[1] = w01.y; wdt[2] = w23.x;
    wdt[3] = w23.y; wdt[4] = w45.x; wdt[5] = w45.y;
    bdt = b_dt[d];
    Dd = D_ssm[d];
    float4 al0 = *(const float4*)&A_log[d * 8];
    float4 al1 = *(const float4*)&A_log[d * 8 + 4];
    a2[0] = -__expf(al0.x) * LOG2E; a2[1] = -__expf(al0.y) * LOG2E;
    a2[2] = -__expf(al0.z) * LOG2E; a2[3] = -__expf(al0.w) * LOG2E;
    a2[4] = -__expf(al1.x) * LOG2E; a2[5] = -__expf(al1.y) * LOG2E;
    a2[6] = -__expf(al1.z) * LOG2E; a2[7] = -__expf(al1.w) * LOG2E;
  }

  // --- causal conv3 + SiLU, IN-PLACE in sxh: reads->regs, barrier, write ---
  {
    const int p  = tid >> 3;
    const int c0 = (tid & 7) * 24;
    bf16x8 xr[3][3];
    #pragma unroll
    for (int g = 0; g < 3; ++g) {
      const int cb0 = c0 + g * 8;
      xr[g][0] = *(const bf16x8*)&sxh[(p + 0) * 200 + cb0];
      xr[g][1] = *(const bf16x8*)&sxh[(p + 1) * 200 + cb0];
      xr[g][2] = *(const bf16x8*)&sxh[(p + 2) * 200 + cb0];
    }
    __syncthreads();                                 // (6) all reads before writes
    #pragma unroll
    for (int g = 0; g < 3; ++g) {
      const int cb0 = c0 + g * 8;
      float wvv[24];
      #pragma unroll
      for (int t = 0; t < 6; ++t)
        *(float4*)&wvv[t * 4] = *(const float4*)&conv_w[cb0 * 3 + t * 4];
      float bv[8];
      *(float4*)&bv[0] = *(const float4*)&conv_b[cb0];
      *(float4*)&bv[4] = *(const float4*)&conv_b[cb0 + 4];
      bf16_t ov[8];
      #pragma unroll
      for (int jj = 0; jj < 8; ++jj) {
        float r = bv[jj] + wvv[jj * 3] * (float)xr[g][0][jj]
                + wvv[jj * 3 + 1] * (float)xr[g][1][jj]
                + wvv[jj * 3 + 2] * (float)xr[g][2][jj];
        ov[jj] = (bf16_t)fast_silu(r);
      }
      *(bf16x8*)&sxh[p * 200 + cb0] = *(bf16x8*)ov;
    }
  }
  __syncthreads();                                   // (7) x' ready

  // --- dbc via MFMA: x'[32x192] @ W_x^T -> sdt/sbc ---
  {
    const int mt = wv >> 1, nt = wv & 1;
    f32x4 acc = {0.f, 0.f, 0.f, 0.f};
    #pragma unroll
    for (int ks = 0; ks < 6; ++ks) {
      bf16x8 Af  = *(const bf16x8*)&sxh[(mt * 16 + nlo) * 200 + ks * 32 + q * 8];
      bf16x8 Bfx = *(const bf16x8*)&Wxb[(nt * 16 + nlo) * 192 + ks * 32 + q * 8];
      acc = __builtin_amdgcn_mfma_f32_16x16x32_bf16(Af, Bfx, acc, 0, 0, 0);
    }
    int n = nt * 16 + nlo;
    #pragma unroll
    for (int r = 0; r < 4; ++r) {
      int p = mt * 16 + q * 4 + r;
      float v = acc[r];
      if (n < 6)       sdt[p * 8 + n] = v;
      else if (n < 14) sbc[p * 16 + (n - 6)] = v;
      else if (n < 22) sbc[p * 16 + 8 + (n - 14)] = v;
    }
  }
  __syncthreads();                                   // (8) sdt/sbc ready

  // --- chunk scan: thread = channel d; delta on the fly; exp2-folded dA ---
  if (tid < 192) {
    const int d = tid;
    float h[8], P[8], K[8];
    #pragma unroll
    for (int s = 0; s < 8; ++s) { h[s] = 0.f; P[s] = 1.f; K[s] = 0.f; }
    float ys = 0.f;

    for (int i = 0; i < CLEN; ++i) {
      float xv = (float)sxh[i * 200 + d];
      float sz = (float)szh[i * 200 + d];
      float4 dt0 = *(const float4*)&sdt[i * 8];
      float2 dt1 = *(const float2*)&sdt[i * 8 + 4];
      float ac = bdt + dt0.x * wdt[0] + dt0.y * wdt[1] + dt0.z * wdt[2]
               + dt0.w * wdt[3] + dt1.x * wdt[4] + dt1.y * wdt[5];
      float E = exp2f(ac * LOG2E);
      float dl = (ac > 15.f) ? ac : LN2 * __log2f(1.f + E);
      float dx = dl * xv;
      float yl = Dd * xv;
      float4 B0 = *(const float4*)&sbc[i * 16];
      float4 B1 = *(const float4*)&sbc[i * 16 + 4];
      float4 C0 = *(const float4*)&sbc[i * 16 + 8];
      float4 C1 = *(const float4*)&sbc[i * 16 + 12];
      float Bv[8] = {B0.x, B0.y, B0.z, B0.w, B1.x, B1.y, B1.z, B1.w};
      float Cv[8] = {C0.x, C0.y, C0.z, C0.w, C1.x, C1.y, C1.z, C1.w};
      #pragma unroll
      for (int s = 0; s < 8; ++s) {
        float dA = exp2f(dl * a2[s]);
        h[s] = dA * h[s] + dx * Bv[s];
        yl  += h[s] * Cv[s];
        P[s] *= dA;
        K[s] += P[s] * Cv[s] * sz;
      }
      ys += yl * sz;
    }
    YP[(b * NCHUNK + c) * 192 + d] = ys;
    const int cb = ((b * NCHUNK + c) * 192 + d) * 8;
    *(float4*)&Pc[cb]     = make_float4(P[0], P[1], P[2], P[3]);
    *(float4*)&Pc[cb + 4] = make_float4(P[4], P[5], P[6], P[7]);
    *(float4*)&Qc[cb]     = make_float4(h[0], h[1], h[2], h[3]);
    *(float4*)&Qc[cb + 4] = make_float4(h[4], h[5], h[6], h[7]);
    *(float4*)&Kc[cb]     = make_float4(K[0], K[1], K[2], K[3]);
    *(float4*)&Kc[cb + 4] = make_float4(K[4], K[5], K[6], K[7]);
  }
}

// ---------------------------------------------------------------------------
// Level-1 combine: thread = (b,seg,d,s); 16 serial chunks, coalesced reads.
// ---------------------------------------------------------------------------
__global__ __launch_bounds__(256) void k_comb1(
    const float* __restrict__ Pc, const float* __restrict__ Qc,
    const float* __restrict__ Kc, float* __restrict__ Pg,
    float* __restrict__ Qg, float* __restrict__ Gg, float* __restrict__ Kg)
{
  int t = blockIdx.x * 256 + threadIdx.x;
  int s = t & 7;
  int rr = t >> 3;
  int d = rr % 192;
  int bs = rr / 192;
  int seg = bs & (NSEG - 1);
  int b = bs >> 3;
  float Pp = 1.f, Hl = 0.f, G = 0.f, Kh = 0.f;
  #pragma unroll 4
  for (int ci = 0; ci < SEGC; ++ci) {
    int o = ((b * NCHUNK + seg * SEGC + ci) * 192 + d) * 8 + s;
    float pv = Pc[o], qv = Qc[o], kv = Kc[o];
    G  += kv * Pp;
    Kh += kv * Hl;
    Hl = pv * Hl + qv;
    Pp *= pv;
  }
  Pg[t] = Pp; Qg[t] = Hl; Gg[t] = G; Kg[t] = Kh;
}

// ---------------------------------------------------------------------------
// Tail: YP/UP reductions + level-2 combine + head. One block per batch.
// ---------------------------------------------------------------------------
__global__ __launch_bounds__(256) void k_head2(
    const float* __restrict__ Pg, const float* __restrict__ Qg,
    const float* __restrict__ Gg, const float* __restrict__ Kg,
    const float* __restrict__ YP, const float* __restrict__ UP,
    const float* __restrict__ W_out, const float* __restrict__ fc_w,
    const float* __restrict__ fc_b, const float* __restrict__ mu_w,
    const float* __restrict__ mu_b, const float* __restrict__ sg_w,
    const float* __restrict__ sg_b, float* __restrict__ out)
{
  const int b = blockIdx.x, tid = threadIdx.x;
  __shared__ float sy[192];
  __shared__ float su2[96];
  __shared__ float e[96];
  __shared__ float tb[256];

  if (tid < 192) {
    float acc = 0.f;
    #pragma unroll 8
    for (int c = 0; c < NCHUNK; ++c) acc += YP[(b * NCHUNK + c) * 192 + tid];
    sy[tid] = acc;
  }
  if (tid < 96) {
    float acc = 0.f;
    #pragma unroll 8
    for (int c = 0; c < NCHUNK; ++c) acc += UP[(b * NCHUNK + c) * 96 + tid];
    su2[tid] = acc;
  }
  __syncthreads();

  #pragma unroll
  for (int ci = 0; ci < 6; ++ci) {
    int cid = ci * 256 + tid;
    int dd = cid >> 3, s = cid & 7;
    float H = 0.f, acc = 0.f;
    #pragma unroll
    for (int seg = 0; seg < NSEG; ++seg) {
      int o = (b * NSEG + seg) * 1536 + cid;
      acc += Gg[o] * H + Kg[o];
      H = Pg[o] * H + Qg[o];
    }
    acc += __shfl_down(acc, 4);
    acc += __shfl_down(acc, 2);
    acc += __shfl_down(acc, 1);
    if (s == 0) atomicAdd(&sy[dd], acc);
  }
  __syncthreads();

  if (tid < 96) {
    const float* wr = W_out + tid * 192;
    float acc = su2[tid];
    #pragma unroll 8
    for (int d = 0; d < 192; ++d) acc += sy[d] * wr[d];
    e[tid] = acc * (1.f / (float)LL);
  }
  __syncthreads();
  {
    const float* wr = fc_w + tid * 96;
    float acc = fc_b[tid];
    #pragma unroll 8
    for (int j = 0; j < 96; ++j) acc += e[j] * wr[j];
    float th = tanhf(acc);
    tb[tid] = (th > 0.f) ? th : expm1f(th);
  }
  __syncthreads();
  if (tid < 64) {
    const float* wr = mu_w + tid * 256;
    float acc = mu_b[tid];
    #pragma unroll 8
    for (int i = 0; i < 256; ++i) acc += tb[i] * wr[i];
    out[b * 64 + tid] = acc;
  } else if (tid < 128) {
    int o = tid - 64;
    const float* wr = sg_w + o * 256;
    float acc = sg_b[o];
    #pragma unroll 8
    for (int i = 0; i < 256; ++i) acc += tb[i] * wr[i];
    float el = (acc > 0.f) ? acc : expm1f(acc);
    out[BB * 64 + b * 64 + o] = el + 1.f + 1e-14f;
  }
}

// ---------------------------------------------------------------------------
extern "C" void kernel_launch(void* const* d_in, const int* in_sizes, int n_in,
                              void* d_out, int out_size, void* d_ws, size_t ws_size,
                              hipStream_t stream)
{
  const float* input  = (const float*)d_in[0];
  const float* norm_w = (const float*)d_in[1];
  const float* W_in   = (const float*)d_in[2];
  const float* conv_w = (const float*)d_in[3];
  const float* conv_b = (const float*)d_in[4];
  const float* W_x    = (const float*)d_in[5];
  const float* W_dt   = (const float*)d_in[6];
  const float* b_dt   = (const float*)d_in[7];
  const float* A_log  = (const float*)d_in[8];
  const float* D_ssm  = (const float*)d_in[9];
  const float* W_out  = (const float*)d_in[10];
  const float* fc_w   = (const float*)d_in[11];
  const float* fc_b   = (const float*)d_in[12];
  const float* mu_w   = (const float*)d_in[13];
  const float* mu_b   = (const float*)d_in[14];
  const float* sg_w   = (const float*)d_in[15];
  const float* sg_b   = (const float*)d_in[16];

  float* ws  = (float*)d_ws;
  float* out = (float*)d_out;
  bf16_t* Wbf = (bf16_t*)(ws + WBF_OFF);
  bf16_t* Wxb = (bf16_t*)(ws + WXB_OFF);

  k_cvt<<<168, 256, 0, stream>>>(W_in, W_x, Wbf, Wxb);
  k_fused<<<BB * NCHUNK, 256, 0, stream>>>(input, norm_w, Wbf, Wxb,
      conv_w, conv_b, W_dt, b_dt, A_log, D_ssm,
      ws + P_OFF, ws + Q_OFF, ws + KC_OFF, ws + YP_OFF, ws + UP_OFF);
  k_comb1<<<(BB * NSEG * 192 * 8) / 256, 256, 0, stream>>>(
      ws + P_OFF, ws + Q_OFF, ws + KC_OFF,
      ws + PG_OFF, ws + QG_OFF, ws + GG_OFF, ws + KG_OFF);
  k_head2<<<BB, 256, 0, stream>>>(
      ws + PG_OFF, ws + QG_OFF, ws + GG_OFF, ws + KG_OFF,
      ws + YP_OFF, ws + UP_OFF, W_out,
      fc_w, fc_b, mu_w, mu_b, sg_w, sg_b, out);
}

// Round 9
// 169.206 us; speedup vs baseline: 1.1404x; 1.1404x over previous
//
#include <hip/hip_runtime.h>
#include <hip/hip_bf16.h>

// Problem constants
#define DM   96
#define DI   192
#define BB   8
#define LL   4096
#define NCHUNK 128
#define CLEN   32
#define NSEG   8
#define SEGC   16
#define LOG2E  1.44269504f
#define LN2    0.69314718f

typedef __bf16 bf16_t;
typedef __attribute__((ext_vector_type(8))) __bf16 bf16x8;
typedef __attribute__((ext_vector_type(4))) __bf16 bf16x4;
typedef __attribute__((ext_vector_type(4))) float f32x4;

// Workspace layout (float offsets)
#define P_OFF    0u         // [B,128,192,8]
#define Q_OFF    786432u
#define KC_OFF   1572864u
#define PG_OFF   2359296u   // [B,8,192,8]
#define QG_OFF   2457600u
#define GG_OFF   2555904u
#define KG_OFF   2654208u
#define YP_OFF   2752512u   // [B,128,192]
#define UP_OFF   2949120u   // [B,128,96]
#define WBF_OFF  3047424u   // bf16 W_in [384][96]
#define WXB_OFF  3065856u   // bf16 W_x  [32pad][192]
#define YP2_OFF  3068928u   // [B,8,192] 8-way partials
#define UP2_OFF  3081216u   // [B,8,96]

// LDS layout (bytes); aliasing across barrier-separated lifetimes (R7-proven):
//   su (fp32 34x100=13600) | szh (bf16 32x200=12800)
//   sa (bf16 48x104= 9984) | sxo (bf16 32x200=12800)
//   sxh (bf16 34x200=13600)| sdt(1024)+sbc(2048)
#define L_SU   0u
#define L_SZH  0u
#define L_SA   13600u
#define L_SXO  13600u
#define L_SXH  26400u
#define L_SDT  26400u
#define L_SBC  27424u
#define L_SSC  40000u
#define L_TOT  40136u    // 4 blocks/CU, all 1024 blocks co-resident

__device__ __forceinline__ float fast_silu(float v) {
  float ev = exp2f(-LOG2E * v);
  return __fdividef(v, 1.f + ev);
}

// ---------------------------------------------------------------------------
// K0: convert W_in -> bf16, W_x -> bf16 [32pad][192].
// ---------------------------------------------------------------------------
__global__ __launch_bounds__(256) void k_cvt(
    const float* __restrict__ W_in, const float* __restrict__ W_x,
    bf16_t* __restrict__ Wbf, bf16_t* __restrict__ Wxb)
{
  int i = blockIdx.x * 256 + threadIdx.x;
  if (i < 36864) Wbf[i] = (bf16_t)W_in[i];
  int j = i - 36864;
  if (j >= 0 && j < 6144) Wxb[j] = (j < 4224) ? (bf16_t)W_x[j] : (bf16_t)0.f;
}

// ---------------------------------------------------------------------------
// Fused (R7-proven form, 58 us): rmsnorm + in-proj MFMA + conv3/silu +
// dbc MFMA + delta + chunk scan. Block = (b, chunk); 256 threads.
// ---------------------------------------------------------------------------
__global__ __launch_bounds__(256, 4) void k_fused(
    const float* __restrict__ u, const float* __restrict__ norm_w,
    const bf16_t* __restrict__ Wbf, const bf16_t* __restrict__ Wxb,
    const float* __restrict__ conv_w, const float* __restrict__ conv_b,
    const float* __restrict__ W_dt, const float* __restrict__ b_dt,
    const float* __restrict__ A_log, const float* __restrict__ D_ssm,
    float* __restrict__ Pc, float* __restrict__ Qc, float* __restrict__ Kc,
    float* __restrict__ YP, float* __restrict__ UP)
{
  __shared__ __align__(16) char lds[L_TOT];
  float*  su  = (float*)(lds + L_SU);
  bf16_t* szh = (bf16_t*)(lds + L_SZH);
  bf16_t* sa  = (bf16_t*)(lds + L_SA);
  bf16_t* sxo = (bf16_t*)(lds + L_SXO);
  bf16_t* sxh = (bf16_t*)(lds + L_SXH);
  float*  sdt = (float*)(lds + L_SDT);
  float*  sbc = (float*)(lds + L_SBC);
  float*  ssc = (float*)(lds + L_SSC);

  const int tid = threadIdx.x;
  const int b   = blockIdx.x >> 7;
  const int c   = blockIdx.x & 127;
  const int wv  = tid >> 6, lane = tid & 63;
  const int q   = lane >> 4, nlo = lane & 15;
  const int l0  = c * CLEN - 2;

  bf16x8 Bf[6][3];
  #pragma unroll
  for (int nt = 0; nt < 6; ++nt)
    #pragma unroll
    for (int ks = 0; ks < 3; ++ks)
      Bf[nt][ks] = *(const bf16x8*)&Wbf[(wv * 96 + nt * 16 + nlo) * 96 + ks * 32 + q * 8];

  for (int i = tid; i < 34 * 24; i += 256) {
    int p = i / 24, k4 = (i - p * 24) * 4;
    int l = l0 + p;
    float4 v = (l >= 0) ? *(const float4*)&u[(b * LL + l) * 96 + k4]
                        : make_float4(0.f, 0.f, 0.f, 0.f);
    *(float4*)&su[p * 100 + k4] = v;
  }
  __syncthreads();

  if (tid < 34) {
    float s = 0.f;
    #pragma unroll
    for (int k4 = 0; k4 < 24; ++k4) {
      float4 v = *(const float4*)&su[tid * 100 + k4 * 4];
      s += v.x * v.x + v.y * v.y + v.z * v.z + v.w * v.w;
    }
    ssc[tid] = rsqrtf(s * (1.f / 96.f) + 1e-5f);
  } else if (tid >= 64 && tid < 160) {
    int k = tid - 64;
    float s = 0.f;
    #pragma unroll 8
    for (int p = 0; p < 32; ++p) s += su[(p + 2) * 100 + k];
    UP[(b * NCHUNK + c) * 96 + k] = s;
  }
  __syncthreads();

  for (int i = tid; i < 34 * 24; i += 256) {
    int p = i / 24, k4 = (i - p * 24) * 4;
    float4 v = *(const float4*)&su[p * 100 + k4];
    float4 nw = *(const float4*)&norm_w[k4];
    float sc = ssc[p];
    bf16x4 o = {(bf16_t)(v.x * sc * nw.x), (bf16_t)(v.y * sc * nw.y),
                (bf16_t)(v.z * sc * nw.z), (bf16_t)(v.w * sc * nw.w)};
    *(bf16x4*)&sa[p * 104 + k4] = o;
  }
  __syncthreads();

  #pragma unroll
  for (int mt = 0; mt < 3; ++mt) {
    const int arow = (mt * 16 + nlo) * 104 + q * 8;
    bf16x8 A0 = *(const bf16x8*)&sa[arow];
    bf16x8 A1 = *(const bf16x8*)&sa[arow + 32];
    bf16x8 A2 = *(const bf16x8*)&sa[arow + 64];
    #pragma unroll
    for (int nt = 0; nt < 6; ++nt) {
      f32x4 acc = {0.f, 0.f, 0.f, 0.f};
      acc = __builtin_amdgcn_mfma_f32_16x16x32_bf16(A0, Bf[nt][0], acc, 0, 0, 0);
      acc = __builtin_amdgcn_mfma_f32_16x16x32_bf16(A1, Bf[nt][1], acc, 0, 0, 0);
      acc = __builtin_amdgcn_mfma_f32_16x16x32_bf16(A2, Bf[nt][2], acc, 0, 0, 0);
      int j = wv * 96 + nt * 16 + nlo;
      int row0 = mt * 16 + q * 4;
      if (j < 192) {
        #pragma unroll
        for (int r = 0; r < 4; ++r) {
          int row = row0 + r;
          if (row < 34) sxh[row * 200 + j] = (bf16_t)acc[r];
        }
      } else {
        int jj = j - 192;
        #pragma unroll
        for (int r = 0; r < 4; ++r) {
          int row = row0 + r;
          if (row >= 2 && row < 34) szh[(row - 2) * 200 + jj] = (bf16_t)fast_silu(acc[r]);
        }
      }
    }
  }
  __syncthreads();

  float wdt[6], bdt = 0.f, Dd = 0.f, a2[8];
  if (tid < 192) {
    const int d = tid;
    float2 w01 = *(const float2*)&W_dt[d * 6];
    float2 w23 = *(const float2*)&W_dt[d * 6 + 2];
    float2 w45 = *(const float2*)&W_dt[d * 6 + 4];
    wdt[0] = w01.x; wdt[1] = w01.y; wdt[2] = w23.x;
    wdt[3] = w23.y; wdt[4] = w45.x; wdt[5] = w45.y;
    bdt = b_dt[d];
    Dd = D_ssm[d];
    float4 al0 = *(const float4*)&A_log[d * 8];
    float4 al1 = *(const float4*)&A_log[d * 8 + 4];
    a2[0] = -__expf(al0.x) * LOG2E; a2[1] = -__expf(al0.y) * LOG2E;
    a2[2] = -__expf(al0.z) * LOG2E; a2[3] = -__expf(al0.w) * LOG2E;
    a2[4] = -__expf(al1.x) * LOG2E; a2[5] = -__expf(al1.y) * LOG2E;
    a2[6] = -__expf(al1.z) * LOG2E; a2[7] = -__expf(al1.w) * LOG2E;
  }

  {
    const int p  = tid >> 3;
    const int c0 = (tid & 7) * 24;
    #pragma unroll
    for (int g = 0; g < 3; ++g) {
      const int cb0 = c0 + g * 8;
      bf16x8 x0 = *(const bf16x8*)&sxh[(p + 0) * 200 + cb0];
      bf16x8 x1 = *(const bf16x8*)&sxh[(p + 1) * 200 + cb0];
      bf16x8 x2 = *(const bf16x8*)&sxh[(p + 2) * 200 + cb0];
      float wvv[24];
      #pragma unroll
      for (int t = 0; t < 6; ++t)
        *(float4*)&wvv[t * 4] = *(const float4*)&conv_w[cb0 * 3 + t * 4];
      float bv[8];
      *(float4*)&bv[0] = *(const float4*)&conv_b[cb0];
      *(float4*)&bv[4] = *(const float4*)&conv_b[cb0 + 4];
      bf16_t ov[8];
      #pragma unroll
      for (int jj = 0; jj < 8; ++jj) {
        float r = bv[jj] + wvv[jj * 3] * (float)x0[jj]
                + wvv[jj * 3 + 1] * (float)x1[jj]
                + wvv[jj * 3 + 2] * (float)x2[jj];
        ov[jj] = (bf16_t)fast_silu(r);
      }
      *(bf16x8*)&sxo[p * 200 + cb0] = *(bf16x8*)ov;
    }
  }
  __syncthreads();

  {
    const int mt = wv >> 1, nt = wv & 1;
    f32x4 acc = {0.f, 0.f, 0.f, 0.f};
    #pragma unroll
    for (int ks = 0; ks < 6; ++ks) {
      bf16x8 Af  = *(const bf16x8*)&sxo[(mt * 16 + nlo) * 200 + ks * 32 + q * 8];
      bf16x8 Bfx = *(const bf16x8*)&Wxb[(nt * 16 + nlo) * 192 + ks * 32 + q * 8];
      acc = __builtin_amdgcn_mfma_f32_16x16x32_bf16(Af, Bfx, acc, 0, 0, 0);
    }
    int n = nt * 16 + nlo;
    #pragma unroll
    for (int r = 0; r < 4; ++r) {
      int p = mt * 16 + q * 4 + r;
      float v = acc[r];
      if (n < 6)       sdt[p * 8 + n] = v;
      else if (n < 14) sbc[p * 16 + (n - 6)] = v;
      else if (n < 22) sbc[p * 16 + 8 + (n - 14)] = v;
    }
  }
  __syncthreads();

  if (tid < 192) {
    const int d = tid;
    float h[8], P[8], K[8];
    #pragma unroll
    for (int s = 0; s < 8; ++s) { h[s] = 0.f; P[s] = 1.f; K[s] = 0.f; }
    float ys = 0.f;

    for (int i = 0; i < CLEN; ++i) {
      float xv = (float)sxo[i * 200 + d];
      float sz = (float)szh[i * 200 + d];
      float4 dt0 = *(const float4*)&sdt[i * 8];
      float2 dt1 = *(const float2*)&sdt[i * 8 + 4];
      float ac = bdt + dt0.x * wdt[0] + dt0.y * wdt[1] + dt0.z * wdt[2]
               + dt0.w * wdt[3] + dt1.x * wdt[4] + dt1.y * wdt[5];
      float E = exp2f(ac * LOG2E);
      float dl = (ac > 15.f) ? ac : LN2 * __log2f(1.f + E);
      float dx = dl * xv;
      float yl = Dd * xv;
      float4 B0 = *(const float4*)&sbc[i * 16];
      float4 B1 = *(const float4*)&sbc[i * 16 + 4];
      float4 C0 = *(const float4*)&sbc[i * 16 + 8];
      float4 C1 = *(const float4*)&sbc[i * 16 + 12];
      float Bv[8] = {B0.x, B0.y, B0.z, B0.w, B1.x, B1.y, B1.z, B1.w};
      float Cv[8] = {C0.x, C0.y, C0.z, C0.w, C1.x, C1.y, C1.z, C1.w};
      #pragma unroll
      for (int s = 0; s < 8; ++s) {
        float dA = exp2f(dl * a2[s]);
        h[s] = dA * h[s] + dx * Bv[s];
        yl  += h[s] * Cv[s];
        P[s] *= dA;
        K[s] += P[s] * Cv[s] * sz;
      }
      ys += yl * sz;
    }
    YP[(b * NCHUNK + c) * 192 + d] = ys;
    const int cb = ((b * NCHUNK + c) * 192 + d) * 8;
    *(float4*)&Pc[cb]     = make_float4(P[0], P[1], P[2], P[3]);
    *(float4*)&Pc[cb + 4] = make_float4(P[4], P[5], P[6], P[7]);
    *(float4*)&Qc[cb]     = make_float4(h[0], h[1], h[2], h[3]);
    *(float4*)&Qc[cb + 4] = make_float4(h[4], h[5], h[6], h[7]);
    *(float4*)&Kc[cb]     = make_float4(K[0], K[1], K[2], K[3]);
    *(float4*)&Kc[cb + 4] = make_float4(K[4], K[5], K[6], K[7]);
  }
}

// ---------------------------------------------------------------------------
// Mid kernel: blocks 0..383 = level-1 combine; 384..431 = YP 8-way partial
// reduction; 432..455 = UP 8-way partial reduction. All coalesced.
// ---------------------------------------------------------------------------
__global__ __launch_bounds__(256) void k_mid(
    const float* __restrict__ Pc, const float* __restrict__ Qc,
    const float* __restrict__ Kc, const float* __restrict__ YP,
    const float* __restrict__ UP, float* __restrict__ Pg,
    float* __restrict__ Qg, float* __restrict__ Gg, float* __restrict__ Kg,
    float* __restrict__ YP2, float* __restrict__ UP2)
{
  const int bid = blockIdx.x, tid = threadIdx.x;
  if (bid < 384) {
    int t = bid * 256 + tid;
    int s = t & 7;
    int rr = t >> 3;
    int d = rr % 192;
    int bs = rr / 192;
    int seg = bs & (NSEG - 1);
    int b = bs >> 3;
    float Pp = 1.f, Hl = 0.f, G = 0.f, Kh = 0.f;
    #pragma unroll 4
    for (int ci = 0; ci < SEGC; ++ci) {
      int o = ((b * NCHUNK + seg * SEGC + ci) * 192 + d) * 8 + s;
      float pv = Pc[o], qv = Qc[o], kv = Kc[o];
      G  += kv * Pp;
      Kh += kv * Hl;
      Hl = pv * Hl + qv;
      Pp *= pv;
    }
    Pg[t] = Pp; Qg[t] = Hl; Gg[t] = G; Kg[t] = Kh;
  } else if (bid < 432) {
    int t = (bid - 384) * 256 + tid;      // [0, 12288)
    int d = t % 192;
    int bs = t / 192;                     // b*8 + slice
    int b = bs >> 3, sl = bs & 7;
    float acc = 0.f;
    #pragma unroll
    for (int i = 0; i < 16; ++i)
      acc += YP[(b * NCHUNK + sl * 16 + i) * 192 + d];
    YP2[t] = acc;
  } else {
    int t = (bid - 432) * 256 + tid;      // [0, 6144)
    int k = t % 96;
    int bs = t / 96;
    int b = bs >> 3, sl = bs & 7;
    float acc = 0.f;
    #pragma unroll
    for (int i = 0; i < 16; ++i)
      acc += UP[(b * NCHUNK + sl * 16 + i) * 96 + k];
    UP2[t] = acc;
  }
}

// ---------------------------------------------------------------------------
// Tail: 8-term partial sums + level-2 combine (seg-outer, 6 chains
// interleaved so loads pipeline) + head. One block per batch.
// ---------------------------------------------------------------------------
__global__ __launch_bounds__(256) void k_head2(
    const float* __restrict__ Pg, const float* __restrict__ Qg,
    const float* __restrict__ Gg, const float* __restrict__ Kg,
    const float* __restrict__ YP2, const float* __restrict__ UP2,
    const float* __restrict__ W_out, const float* __restrict__ fc_w,
    const float* __restrict__ fc_b, const float* __restrict__ mu_w,
    const float* __restrict__ mu_b, const float* __restrict__ sg_w,
    const float* __restrict__ sg_b, float* __restrict__ out)
{
  const int b = blockIdx.x, tid = threadIdx.x;
  __shared__ float sy[192];
  __shared__ float su2[96];
  __shared__ float e[96];
  __shared__ float tb[256];

  if (tid < 192) {
    float acc = 0.f;
    #pragma unroll
    for (int s8 = 0; s8 < 8; ++s8) acc += YP2[(b * 8 + s8) * 192 + tid];
    sy[tid] = acc;
  }
  if (tid < 96) {
    float acc = 0.f;
    #pragma unroll
    for (int s8 = 0; s8 < 8; ++s8) acc += UP2[(b * 8 + s8) * 96 + tid];
    su2[tid] = acc;
  }
  __syncthreads();

  // level-2 combine: 6 independent chains per thread, seg-outer so the
  // 24 loads per round issue together (latency pipelined).
  {
    float H[6], ac2[6];
    #pragma unroll
    for (int ci = 0; ci < 6; ++ci) { H[ci] = 0.f; ac2[ci] = 0.f; }
    for (int seg = 0; seg < NSEG; ++seg) {
      #pragma unroll
      for (int ci = 0; ci < 6; ++ci) {
        int o = (b * NSEG + seg) * 1536 + ci * 256 + tid;
        ac2[ci] += Gg[o] * H[ci] + Kg[o];
        H[ci] = Pg[o] * H[ci] + Qg[o];
      }
    }
    #pragma unroll
    for (int ci = 0; ci < 6; ++ci) {
      float acc = ac2[ci];
      acc += __shfl_down(acc, 4);
      acc += __shfl_down(acc, 2);
      acc += __shfl_down(acc, 1);
      if ((tid & 7) == 0) atomicAdd(&sy[(ci * 256 + tid) >> 3], acc);
    }
  }
  __syncthreads();

  if (tid < 96) {
    const float* wr = W_out + tid * 192;
    float acc = su2[tid];
    #pragma unroll 8
    for (int d = 0; d < 192; ++d) acc += sy[d] * wr[d];
    e[tid] = acc * (1.f / (float)LL);
  }
  __syncthreads();
  {
    const float* wr = fc_w + tid * 96;
    float acc = fc_b[tid];
    #pragma unroll 8
    for (int j = 0; j < 96; ++j) acc += e[j] * wr[j];
    float th = tanhf(acc);
    tb[tid] = (th > 0.f) ? th : expm1f(th);
  }
  __syncthreads();
  if (tid < 64) {
    const float* wr = mu_w + tid * 256;
    float acc = mu_b[tid];
    #pragma unroll 8
    for (int i = 0; i < 256; ++i) acc += tb[i] * wr[i];
    out[b * 64 + tid] = acc;
  } else if (tid < 128) {
    int o = tid - 64;
    const float* wr = sg_w + o * 256;
    float acc = sg_b[o];
    #pragma unroll 8
    for (int i = 0; i < 256; ++i) acc += tb[i] * wr[i];
    float el = (acc > 0.f) ? acc : expm1f(acc);
    out[BB * 64 + b * 64 + o] = el + 1.f + 1e-14f;
  }
}

// ---------------------------------------------------------------------------
extern "C" void kernel_launch(void* const* d_in, const int* in_sizes, int n_in,
                              void* d_out, int out_size, void* d_ws, size_t ws_size,
                              hipStream_t stream)
{
  const float* input  = (const float*)d_in[0];
  const float* norm_w = (const float*)d_in[1];
  const float* W_in   = (const float*)d_in[2];
  const float* conv_w = (const float*)d_in[3];
  const float* conv_b = (const float*)d_in[4];
  const float* W_x    = (const float*)d_in[5];
  const float* W_dt   = (const float*)d_in[6];
  const float* b_dt   = (const float*)d_in[7];
  const float* A_log  = (const float*)d_in[8];
  const float* D_ssm  = (const float*)d_in[9];
  const float* W_out  = (const float*)d_in[10];
  const float* fc_w   = (const float*)d_in[11];
  const float* fc_b   = (const float*)d_in[12];
  const float* mu_w   = (const float*)d_in[13];
  const float* mu_b   = (const float*)d_in[14];
  const float* sg_w   = (const float*)d_in[15];
  const float* sg_b   = (const float*)d_in[16];

  float* ws  = (float*)d_ws;
  float* out = (float*)d_out;
  bf16_t* Wbf = (bf16_t*)(ws + WBF_OFF);
  bf16_t* Wxb = (bf16_t*)(ws + WXB_OFF);

  k_cvt<<<168, 256, 0, stream>>>(W_in, W_x, Wbf, Wxb);
  k_fused<<<BB * NCHUNK, 256, 0, stream>>>(input, norm_w, Wbf, Wxb,
      conv_w, conv_b, W_dt, b_dt, A_log, D_ssm,
      ws + P_OFF, ws + Q_OFF, ws + KC_OFF, ws + YP_OFF, ws + UP_OFF);
  k_mid<<<456, 256, 0, stream>>>(
      ws + P_OFF, ws + Q_OFF, ws + KC_OFF, ws + YP_OFF, ws + UP_OFF,
      ws + PG_OFF, ws + QG_OFF, ws + GG_OFF, ws + KG_OFF,
      ws + YP2_OFF, ws + UP2_OFF);
  k_head2<<<BB, 256, 0, stream>>>(
      ws + PG_OFF, ws + QG_OFF, ws + GG_OFF, ws + KG_OFF,
      ws + YP2_OFF, ws + UP2_OFF, W_out,
      fc_w, fc_b, mu_w, mu_b, sg_w, sg_b, out);
}